// Round 22
// baseline (102.628 us; speedup 1.0000x reference)
//
#include <hip/hip_runtime.h>

typedef __attribute__((ext_vector_type(8))) _Float16 f16x8;
typedef __attribute__((ext_vector_type(4))) float f32x4;

#define HSTR 264   // fp16 per A/C row (528B): 16B-aligned, staggered banks

__device__ __forceinline__ void gload_lds16(const void* g, void* l) {
  __builtin_amdgcn_global_load_lds(
      (const __attribute__((address_space(1))) void*)g,
      (__attribute__((address_space(3))) void*)l, 16, 0, 0);
}

// ---- prep: weights -> fp16, fragment-contiguous (lane-major) into d_ws ----
__global__ __launch_bounds__(256) void prep_kernel(
    const float* __restrict__ gW0, const float* __restrict__ gW1,
    _Float16* __restrict__ W0c, _Float16* __restrict__ W1c)
{
  const int t = blockIdx.x * 256 + threadIdx.x;  // 0..65535
  {
    const int c = t >> 7, k = t & 127;           // c in [0,512), k in [0,128)
    const int dst = ((k >> 5) * 32 + (c >> 4)) * 512 +
                    (((k >> 3) & 3) * 16 + (c & 15)) * 8 + (k & 7);
    const int src = (k + ((c >= 256) ? 128 : 0)) * 256 + (c & 255);
    W0c[dst] = (_Float16)gW0[src];
  }
  {
    const int n = t >> 8, k = t & 255;           // n in [0,256), k in [0,256)
    const int dst = ((k >> 5) * 16 + (n >> 4)) * 512 +
                    (((k >> 3) & 3) * 16 + (n & 15)) * 8 + (k & 7);
    W1c[dst] = (_Float16)gW1[k * 256 + n];
  }
}

// ---- main: weights-from-LDS, 2 N-passes, M-split=8, NO pin ----
// r10-r21 synthesis: remat forms are L2-BW-bound (2GB/dispatch ~ 34TB/s =
// their 55-59us); pinned forms leave 64 VGPRs -> compiler can't hoist
// ds_reads -> latency-serialized 57us. This structure avoids both walls:
// W1 staged per 128-col pass into 64KB LDS (frag-contiguous, lane-linear,
// global_load_lds) -- weights never occupy registers and never re-stream
// from L2; full 128-VGPR class is free for the scheduler to pipeline.
// Wave w owns tiles {2w, 2w+1}; per kk: build u0,u1; per nt: 1 ds_read
// frag -> 2 MFMAs (frag reuse across the tile pair). nt-split=2 keeps
// acc at 32 VGPR (8 indep chains x len 8). ~105 VGPR, 2 blocks/CU.
__global__ __launch_bounds__(512, 4) void pair_kernel(
    const float* __restrict__ state,
    const _Float16* __restrict__ W0c, const float* __restrict__ gb0,
    const _Float16* __restrict__ W1c, const float* __restrict__ gb1,
    float* __restrict__ pooled)
{
  const int b   = blockIdx.x;
  const int tid = threadIdx.x;
  const int w   = tid >> 6;   // wave 0..7
  const int l   = tid & 63;
  const int lr  = l & 15;
  const int lg  = l >> 4;

  // [0,8448) A_lds; [8448, +65536) wbuf (C staged there first); [+4096) pool
  __shared__ __align__(16) char smem[8448 + 65536 + 4096];
  _Float16* A_lds = (_Float16*)smem;
  char*     wbuf  = smem + 8448;
  _Float16* C_st  = (_Float16*)wbuf;   // staging overlay, dead after creg capture
  float*    pool  = (float*)(smem + 8448 + 65536);

  const float* stb = state + (size_t)b * 2048;

  // ---------------- Phase 2: [A|C] = state[16x128] @ W0 (fp16 MFMA) ----------------
  f16x8 sfrag[4];
  #pragma unroll
  for (int kk = 0; kk < 4; ++kk) {
    const float* sp = stb + lr * 128 + kk * 32 + lg * 8;
    f32x4 s0 = *(const f32x4*)sp;
    f32x4 s1 = *(const f32x4*)(sp + 4);
    f16x8 f;
    f[0] = (_Float16)s0[0]; f[1] = (_Float16)s0[1];
    f[2] = (_Float16)s0[2]; f[3] = (_Float16)s0[3];
    f[4] = (_Float16)s1[0]; f[5] = (_Float16)s1[1];
    f[6] = (_Float16)s1[2]; f[7] = (_Float16)s1[3];
    sfrag[kk] = f;
  }

  const f32x4 z4 = {0.f, 0.f, 0.f, 0.f};
  f32x4 acc2[4];
  #pragma unroll
  for (int nt = 0; nt < 4; ++nt) acc2[nt] = z4;

  // wave w owns [A|C] cols [64w, 64w+64) for phase 2
  #pragma unroll
  for (int nt = 0; nt < 4; ++nt) {
    #pragma unroll
    for (int kk = 0; kk < 4; ++kk) {
      f16x8 bf = *(const f16x8*)(W0c + (size_t)((kk * 32 + 4 * w + nt) * 512 + l * 8));
      acc2[nt] = __builtin_amdgcn_mfma_f32_16x16x32_f16(sfrag[kk], bf, acc2[nt], 0, 0, 0);
    }
  }

  // store phase-2 results as fp16 (C/D layout: col=lr, row=lg*4+r); fold gb0
  #pragma unroll
  for (int nt = 0; nt < 4; ++nt) {
    const int col = 64 * w + 16 * nt + lr;
    #pragma unroll
    for (int r = 0; r < 4; ++r) {
      const int row = lg * 4 + r;
      const float v = acc2[nt][r];
      if (col < 256) A_lds[row * HSTR + col]       = (_Float16)(v + gb0[col]);
      else           C_st[row * HSTR + col - 256]  = (_Float16)v;
    }
  }
  __syncthreads();

  // creg: full k, lane (lr,lg) holds C[lr][kk*32+lg*8 .. +8] -> 32 VGPR
  f16x8 creg[8];
  #pragma unroll
  for (int kk = 0; kk < 8; ++kk)
    creg[kk] = *(const f16x8*)&C_st[lr * HSTR + kk * 32 + lg * 8];
  __syncthreads();   // C_st dead; wbuf writable

  // stage pass-0 weights (cols 0-127): 64 frags of 1KB, frag f=(kk*8+nt) at
  // wbuf+f*1024, lane-linear. Wave w loads frags {8w..8w+7}.
  #pragma unroll
  for (int j = 0; j < 8; ++j) {
    const int f  = w * 8 + j;                    // kk = f>>3, nt = f&7
    const int fs = (f >> 3) * 16 + (f & 7);      // pass 0: global frag idx
    gload_lds16((const char*)W1c + (size_t)fs * 1024 + l * 16,
                wbuf + (size_t)f * 1024);
  }
  __syncthreads();   // weights visible (barrier drains vmcnt)

  const f16x8 zh = {(_Float16)0, (_Float16)0, (_Float16)0, (_Float16)0,
                    (_Float16)0, (_Float16)0, (_Float16)0, (_Float16)0};
  const int i0 = 2 * w, i1 = 2 * w + 1;   // this wave's tiles

  #pragma unroll 1
  for (int p = 0; p < 2; ++p) {
    float pp[8];
    #pragma unroll
    for (int nt = 0; nt < 8; ++nt) pp[nt] = 0.f;

    // ---- compute this pass: 2 nt-halves of 4 cols-of-16 each ----
    #pragma unroll
    for (int nh = 0; nh < 2; ++nh) {
      f32x4 a0[4], a1[4];
      #pragma unroll
      for (int nt = 0; nt < 4; ++nt) { a0[nt] = z4; a1[nt] = z4; }

      #pragma unroll
      for (int kk = 0; kk < 8; ++kk) {
        f16x8 av0 = *(const f16x8*)&A_lds[i0 * HSTR + kk * 32 + lg * 8];
        f16x8 av1 = *(const f16x8*)&A_lds[i1 * HSTR + kk * 32 + lg * 8];
        f16x8 u0 = __builtin_elementwise_max(av0 + creg[kk], zh);
        f16x8 u1 = __builtin_elementwise_max(av1 + creg[kk], zh);
        #pragma unroll
        for (int nt = 0; nt < 4; ++nt) {
          f16x8 wf = *(const f16x8*)(wbuf + (size_t)((kk * 8 + nh * 4 + nt) * 1024) + l * 16);
          a0[nt] = __builtin_amdgcn_mfma_f32_16x16x32_f16(u0, wf, a0[nt], 0, 0, 0);
          a1[nt] = __builtin_amdgcn_mfma_f32_16x16x32_f16(u1, wf, a1[nt], 0, 0, 0);
        }
      }

      #pragma unroll
      for (int nt = 0; nt < 4; ++nt) {
        const float gb = gb1[p * 128 + (nh * 4 + nt) * 16 + lr];
        float s = 0.f;
        #pragma unroll
        for (int r = 0; r < 4; ++r) {
          const int row = lg * 4 + r;       // = j
          const float v0 = fmaxf(a0[nt][r] + gb, 0.f);
          const float v1 = fmaxf(a1[nt][r] + gb, 0.f);
          s += (row == i0) ? 0.f : v0;      // mask the (i,i) filler pair
          s += (row == i1) ? 0.f : v1;
        }
        pp[nh * 4 + nt] = s;
      }
    }

    // lane-group reduce -> pool[w][128]
    #pragma unroll
    for (int nt = 0; nt < 8; ++nt) {
      float v = pp[nt];
      v += __shfl_xor(v, 16);
      v += __shfl_xor(v, 32);
      if (lg == 0) pool[w * 128 + nt * 16 + lr] = v;
    }
    __syncthreads();   // all waves done with wbuf + pool complete

    // cross-wave sum -> global; meanwhile stage pass-1 weights
    if (p == 0) {
      #pragma unroll
      for (int j = 0; j < 8; ++j) {
        const int f  = w * 8 + j;
        const int fs = (f >> 3) * 16 + 8 + (f & 7);   // pass 1 frags
        gload_lds16((const char*)W1c + (size_t)fs * 1024 + l * 16,
                    wbuf + (size_t)f * 1024);
      }
    }
    if (tid < 128) {
      float s = 0.f;
      #pragma unroll
      for (int w8 = 0; w8 < 8; ++w8) s += pool[w8 * 128 + tid];
      pooled[(size_t)b * 256 + p * 128 + tid] = s;
    }
    __syncthreads();   // pass-1 weights visible / pool consumed
  }
}

// ---- f-MLP: 256 blocks x 4 batches (r15 form -- best measured total) ----
__global__ __launch_bounds__(256) void fmlp_kernel(
    const float* __restrict__ pooled,
    const float* __restrict__ fW0, const float* __restrict__ fb0,
    const float* __restrict__ fW1, const float* __restrict__ fb1,
    float* __restrict__ out)
{
  const int tid = threadIdx.x;
  const size_t b0 = (size_t)blockIdx.x * 4;
  __shared__ float pl[4][256];
  __shared__ float h1[4][256];

  #pragma unroll
  for (int q = 0; q < 4; ++q)
    pl[q][tid] = pooled[(b0 + q) * 256 + tid];
  __syncthreads();

  float acc[4] = {0.f, 0.f, 0.f, 0.f};
  #pragma unroll 8
  for (int k = 0; k < 256; ++k) {
    const float wv = fW0[(size_t)k * 256 + tid];
    #pragma unroll
    for (int q = 0; q < 4; ++q) acc[q] = fmaf(pl[q][k], wv, acc[q]);
  }
  #pragma unroll
  for (int q = 0; q < 4; ++q) h1[q][tid] = fmaxf(acc[q] + fb0[tid], 0.f);
  __syncthreads();

  float acc2[4] = {0.f, 0.f, 0.f, 0.f};
  #pragma unroll 8
  for (int k = 0; k < 256; ++k) {
    const float wv = fW1[(size_t)k * 256 + tid];
    #pragma unroll
    for (int q = 0; q < 4; ++q) acc2[q] = fmaf(h1[q][k], wv, acc2[q]);
  }
  #pragma unroll
  for (int q = 0; q < 4; ++q)
    out[(b0 + q) * 256 + tid] = fmaxf(acc2[q] + fb1[tid], 0.f);
}

extern "C" void kernel_launch(void* const* d_in, const int* in_sizes, int n_in,
                              void* d_out, int out_size, void* d_ws, size_t ws_size,
                              hipStream_t stream) {
  const float* state = (const float*)d_in[0];
  const float* gW0   = (const float*)d_in[1];
  const float* gb0   = (const float*)d_in[2];
  const float* gW1   = (const float*)d_in[3];
  const float* gb1   = (const float*)d_in[4];
  const float* fW0   = (const float*)d_in[5];
  const float* fb0   = (const float*)d_in[6];
  const float* fW1   = (const float*)d_in[7];
  const float* fb1   = (const float*)d_in[8];
  float* out = (float*)d_out;

  _Float16* W0c = (_Float16*)d_ws;                      // 65536 fp16 = 128KB
  _Float16* W1c = W0c + 65536;                          // 65536 fp16 = 128KB
  float* pooled = (float*)(W1c + 65536);                // 1024*256 f32 = 1MB

  const int Bn = in_sizes[0] / 2048;  // 1024

  prep_kernel<<<dim3(256), dim3(256), 0, stream>>>(gW0, gW1, W0c, W1c);
  pair_kernel<<<dim3(Bn), dim3(512), 0, stream>>>(state, W0c, gb0, W1c, gb1, pooled);
  fmlp_kernel<<<dim3(Bn / 4), dim3(256), 0, stream>>>(pooled, fW0, fb0, fW1, fb1, out);
}

// Round 23
// 84.331 us; speedup vs baseline: 1.2170x; 1.2170x over previous
//
#include <hip/hip_runtime.h>

typedef __attribute__((ext_vector_type(8))) _Float16 f16x8;
typedef __attribute__((ext_vector_type(4))) float f32x4;

#define HSTR 264   // fp16 per A/C row (528B): 16B-aligned, staggered banks

// ---- prep: weights -> fp16, fragment-contiguous (lane-major) into d_ws ----
__global__ __launch_bounds__(256) void prep_kernel(
    const float* __restrict__ gW0, const float* __restrict__ gW1,
    _Float16* __restrict__ W0c, _Float16* __restrict__ W1c)
{
  const int t = blockIdx.x * 256 + threadIdx.x;  // 0..65535
  {
    const int c = t >> 7, k = t & 127;           // c in [0,512), k in [0,128)
    const int dst = ((k >> 5) * 32 + (c >> 4)) * 512 +
                    (((k >> 3) & 3) * 16 + (c & 15)) * 8 + (k & 7);
    const int src = (k + ((c >= 256) ? 128 : 0)) * 256 + (c & 255);
    W0c[dst] = (_Float16)gW0[src];
  }
  {
    const int n = t >> 8, k = t & 255;           // n in [0,256), k in [0,256)
    const int dst = ((k >> 5) * 16 + (n >> 4)) * 512 +
                    (((k >> 3) & 3) * 16 + (n & 15)) * 8 + (k & 7);
    W1c[dst] = (_Float16)gW1[k * 256 + n];
  }
}

// ---- main: r10 barrier-free structure + i-PAIR weight-fragment reuse ----
// 22-round model: r10 (55.3us, fastest) is exactly L2-BW-bound -- its remat
// weight loads stream 2GB/dispatch = 36TB/s = the L2 ceiling. Pinned forms
// kill the stream but strand the scheduler at 64 VGPRs (57.4us latency-
// bound). This round keeps r10 VERBATIM except phase 3 processes i-tiles in
// PAIRS: one weight-fragment load feeds 2 MFMAs (i0,i1) -> L2 traffic
// halves to 1GB (~29us), below the MFMA/VALU budgets. creg overflow can
// remat from the persistent C_lds (cheap ds_read) instead of scratch.
__global__ __launch_bounds__(512, 4) void pair_kernel(
    const float* __restrict__ state,
    const _Float16* __restrict__ W0c, const float* __restrict__ gb0,
    const _Float16* __restrict__ W1c, const float* __restrict__ gb1,
    float* __restrict__ pooled)
{
  const int b   = blockIdx.x;
  const int tid = threadIdx.x;
  const int w   = tid >> 6;   // wave 0..7
  const int l   = tid & 63;
  const int lr  = l & 15;
  const int lg  = l >> 4;

  __shared__ _Float16 A_lds[16 * HSTR];
  __shared__ _Float16 C_lds[16 * HSTR];

  const float* stb = state + (size_t)b * 2048;

  // ---------------- Phase 2: [A|C] = state[16x128] @ W0 (fp16 MFMA) ----------------
  f16x8 sfrag[4];
  #pragma unroll
  for (int kk = 0; kk < 4; ++kk) {
    const float* sp = stb + lr * 128 + kk * 32 + lg * 8;
    f32x4 s0 = *(const f32x4*)sp;
    f32x4 s1 = *(const f32x4*)(sp + 4);
    f16x8 f;
    f[0] = (_Float16)s0[0]; f[1] = (_Float16)s0[1];
    f[2] = (_Float16)s0[2]; f[3] = (_Float16)s0[3];
    f[4] = (_Float16)s1[0]; f[5] = (_Float16)s1[1];
    f[6] = (_Float16)s1[2]; f[7] = (_Float16)s1[3];
    sfrag[kk] = f;
  }

  const f32x4 z4 = {0.f, 0.f, 0.f, 0.f};
  f32x4 acc2[4];
  #pragma unroll
  for (int nt = 0; nt < 4; ++nt) acc2[nt] = z4;

  // wave w owns [A|C] cols [64w, 64w+64) for phase 2
  #pragma unroll
  for (int nt = 0; nt < 4; ++nt) {
    #pragma unroll
    for (int kk = 0; kk < 4; ++kk) {
      f16x8 bf = *(const f16x8*)(W0c + (size_t)((kk * 32 + 4 * w + nt) * 512 + l * 8));
      acc2[nt] = __builtin_amdgcn_mfma_f32_16x16x32_f16(sfrag[kk], bf, acc2[nt], 0, 0, 0);
    }
  }

  float gb1v[2];
  gb1v[0] = gb1[32 * w + lr];
  gb1v[1] = gb1[32 * w + 16 + lr];

  // store phase-2 results as fp16 (C/D layout: col=lr, row=lg*4+r); fold gb0
  #pragma unroll
  for (int nt = 0; nt < 4; ++nt) {
    const int col = 64 * w + 16 * nt + lr;
    #pragma unroll
    for (int r = 0; r < 4; ++r) {
      const int row = lg * 4 + r;
      const float v = acc2[nt][r];
      if (col < 256) A_lds[row * HSTR + col]       = (_Float16)(v + gb0[col]);
      else           C_lds[row * HSTR + col - 256] = (_Float16)v;
    }
  }
  __syncthreads();

  // creg: full k, lane (lr,lg) holds C[lr][kk*32+lg*8 .. +8] -> 32 VGPR
  // (C_lds persists, so the allocator may re-read instead of spilling)
  f16x8 creg[8];
  #pragma unroll
  for (int kk = 0; kk < 8; ++kk)
    creg[kk] = *(const f16x8*)&C_lds[lr * HSTR + kk * 32 + lg * 8];

  const f16x8 zh = {(_Float16)0, (_Float16)0, (_Float16)0, (_Float16)0,
                    (_Float16)0, (_Float16)0, (_Float16)0, (_Float16)0};

  // ---------------- Phase 3: barrier-free, i-tiles in PAIRS ----------------
  // per (pair, kk): 2 u-builds; per nt: ONE weight-frag load -> 2 MFMAs.
  // Weight L2 traffic halves vs r10 (each frag value has 2 uses).
  float pp0 = 0.f, pp1 = 0.f;
  #pragma unroll 1
  for (int ip = 0; ip < 8; ++ip) {
    const int i0 = 2 * ip, i1 = 2 * ip + 1;
    f32x4 a00 = z4, a01 = z4, a10 = z4, a11 = z4;
    #pragma unroll
    for (int kk = 0; kk < 8; ++kk) {
      f16x8 av0 = *(const f16x8*)&A_lds[i0 * HSTR + kk * 32 + lg * 8];  // bcast
      f16x8 av1 = *(const f16x8*)&A_lds[i1 * HSTR + kk * 32 + lg * 8];
      f16x8 u0 = __builtin_elementwise_max(av0 + creg[kk], zh);
      f16x8 u1 = __builtin_elementwise_max(av1 + creg[kk], zh);
      {
        f16x8 wf = *(const f16x8*)(W1c + (size_t)((kk * 16 + 2 * w) * 512 + l * 8));
        a00 = __builtin_amdgcn_mfma_f32_16x16x32_f16(u0, wf, a00, 0, 0, 0);
        a10 = __builtin_amdgcn_mfma_f32_16x16x32_f16(u1, wf, a10, 0, 0, 0);
      }
      {
        f16x8 wf = *(const f16x8*)(W1c + (size_t)((kk * 16 + 2 * w + 1) * 512 + l * 8));
        a01 = __builtin_amdgcn_mfma_f32_16x16x32_f16(u0, wf, a01, 0, 0, 0);
        a11 = __builtin_amdgcn_mfma_f32_16x16x32_f16(u1, wf, a11, 0, 0, 0);
      }
    }
    #pragma unroll
    for (int r = 0; r < 4; ++r) {
      const int row = lg * 4 + r;       // = j
      const float v00 = fmaxf(a00[r] + gb1v[0], 0.f);
      const float v01 = fmaxf(a01[r] + gb1v[1], 0.f);
      const float v10 = fmaxf(a10[r] + gb1v[0], 0.f);
      const float v11 = fmaxf(a11[r] + gb1v[1], 0.f);
      pp0 += (row == i0) ? 0.f : v00;   // mask the (i,i) filler pair
      pp1 += (row == i0) ? 0.f : v01;
      pp0 += (row == i1) ? 0.f : v10;
      pp1 += (row == i1) ? 0.f : v11;
    }
  }

  // reduce the 4 lane-groups (disjoint j subsets, same col), write pooled
  {
    float v = pp0;
    v += __shfl_xor(v, 16);
    v += __shfl_xor(v, 32);
    if (lg == 0) pooled[(size_t)b * 256 + 32 * w + lr] = v;
  }
  {
    float v = pp1;
    v += __shfl_xor(v, 16);
    v += __shfl_xor(v, 32);
    if (lg == 0) pooled[(size_t)b * 256 + 32 * w + 16 + lr] = v;
  }
}

// ---- f-MLP: 256 blocks x 4 batches (r15 form -- best measured total) ----
__global__ __launch_bounds__(256) void fmlp_kernel(
    const float* __restrict__ pooled,
    const float* __restrict__ fW0, const float* __restrict__ fb0,
    const float* __restrict__ fW1, const float* __restrict__ fb1,
    float* __restrict__ out)
{
  const int tid = threadIdx.x;
  const size_t b0 = (size_t)blockIdx.x * 4;
  __shared__ float pl[4][256];
  __shared__ float h1[4][256];

  #pragma unroll
  for (int q = 0; q < 4; ++q)
    pl[q][tid] = pooled[(b0 + q) * 256 + tid];
  __syncthreads();

  float acc[4] = {0.f, 0.f, 0.f, 0.f};
  #pragma unroll 8
  for (int k = 0; k < 256; ++k) {
    const float wv = fW0[(size_t)k * 256 + tid];
    #pragma unroll
    for (int q = 0; q < 4; ++q) acc[q] = fmaf(pl[q][k], wv, acc[q]);
  }
  #pragma unroll
  for (int q = 0; q < 4; ++q) h1[q][tid] = fmaxf(acc[q] + fb0[tid], 0.f);
  __syncthreads();

  float acc2[4] = {0.f, 0.f, 0.f, 0.f};
  #pragma unroll 8
  for (int k = 0; k < 256; ++k) {
    const float wv = fW1[(size_t)k * 256 + tid];
    #pragma unroll
    for (int q = 0; q < 4; ++q) acc2[q] = fmaf(h1[q][k], wv, acc2[q]);
  }
  #pragma unroll
  for (int q = 0; q < 4; ++q)
    out[(b0 + q) * 256 + tid] = fmaxf(acc2[q] + fb1[tid], 0.f);
}

extern "C" void kernel_launch(void* const* d_in, const int* in_sizes, int n_in,
                              void* d_out, int out_size, void* d_ws, size_t ws_size,
                              hipStream_t stream) {
  const float* state = (const float*)d_in[0];
  const float* gW0   = (const float*)d_in[1];
  const float* gb0   = (const float*)d_in[2];
  const float* gW1   = (const float*)d_in[3];
  const float* gb1   = (const float*)d_in[4];
  const float* fW0   = (const float*)d_in[5];
  const float* fb0   = (const float*)d_in[6];
  const float* fW1   = (const float*)d_in[7];
  const float* fb1   = (const float*)d_in[8];
  float* out = (float*)d_out;

  _Float16* W0c = (_Float16*)d_ws;                      // 65536 fp16 = 128KB
  _Float16* W1c = W0c + 65536;                          // 65536 fp16 = 128KB
  float* pooled = (float*)(W1c + 65536);                // 1024*256 f32 = 1MB

  const int Bn = in_sizes[0] / 2048;  // 1024

  prep_kernel<<<dim3(256), dim3(256), 0, stream>>>(gW0, gW1, W0c, W1c);
  pair_kernel<<<dim3(Bn), dim3(512), 0, stream>>>(state, W0c, gb0, W1c, gb1, pooled);
  fmlp_kernel<<<dim3(Bn / 4), dim3(256), 0, stream>>>(pooled, fW0, fb0, fW1, fb1, out);
}